// Round 1
// baseline (145.881 us; speedup 1.0000x reference)
//
#include <hip/hip_runtime.h>

#define CDIM 64
#define TDIM 24
#define NDIM 512
#define NBT  192   // B*T = 8*24

typedef float    float4v __attribute__((ext_vector_type(4)));
typedef _Float16 half8v  __attribute__((ext_vector_type(8)));
typedef _Float16 half2v  __attribute__((ext_vector_type(2)));

// ---------------------------------------------------------------------------
// Workspace layout (bytes):
//   VT_g    : _Float16 [NBT][64][512]   0          .. 12582912
//   s_src_g : float    [NBT][2][512]    12582912   .. 13369344
//   s_dst_g : float    [NBT][2][512]    13369344   .. 14155776
//   bits_g  : uint     [16][512]        14155776   .. 14188544
// ---------------------------------------------------------------------------

// ============ kernel 0: pack gso (N x N int) into bitmask, layout [ks][i] ====
__global__ void k0_maskbits(const int* __restrict__ gso, unsigned* __restrict__ bits) {
  int tg = blockIdx.x * 256 + threadIdx.x;   // 8192 words total
  int i  = tg >> 4;
  int ks = tg & 15;
  const int* row = gso + i * NDIM + ks * 32;
  unsigned w = 0;
#pragma unroll
  for (int b = 0; b < 32; ++b) w |= (row[b] != 0 ? (1u << b) : 0u);
  bits[ks * NDIM + i] = w;
}

// ============ kernel 1: V = X @ Wv^T (f16 MFMA), s_src/s_dst as extra cols ===
// grid (2, NBT): blockIdx.x = node-half (256 nodes), blockIdx.y = bt
struct SmemK1 {
  union {
    _Float16 xt[256][72];   // X tile  [node][c]   (rows 144 B, 16B aligned)
    _Float16 vt[64][264];   // V^T bounce [c][node]
  } big;                    // 36864 B
  _Float16 wv[64][72];      // Wv [d][k]           9216 B
  _Float16 wext[16][72];    // rows 0..3 = wsrc0,wsrc1,wdst0,wdst1   2304 B
};

__launch_bounds__(256, 2)
__global__ void k1_qkv(const float* __restrict__ x,  const float* __restrict__ Wq,
                       const float* __restrict__ Wk, const float* __restrict__ Wv,
                       const float* __restrict__ a_src, const float* __restrict__ a_dst,
                       _Float16* __restrict__ VT_g,
                       float* __restrict__ s_src_g, float* __restrict__ s_dst_g) {
  __shared__ SmemK1 sm;
  const int t    = threadIdx.x;
  const int half = blockIdx.x;
  const int bt   = blockIdx.y;
  const int b    = bt / TDIM, tt = bt % TDIM;
  const int n0   = half * 256;

  // stage Wv -> f16 LDS
  for (int it = 0; it < 16; ++it) {
    int idx = it * 256 + t;
    int d = idx >> 6, k = idx & 63;
    sm.wv[d][k] = (_Float16)Wv[idx];
  }
  // stage X tile: pairs of channels packed as half2 (coalesced global reads)
  for (int it = 0; it < 32; ++it) {
    int idx = it * 256 + t;      // 8192 pairs
    int cp  = idx >> 8;          // channel pair 0..31
    int n   = idx & 255;
    int c0  = cp * 2;
    const float* base = x + ((size_t)(b * CDIM + c0) * TDIM + tt) * NDIM + n0 + n;
    float v0 = base[0];
    float v1 = base[(size_t)TDIM * NDIM];
    half2v p; p[0] = (_Float16)v0; p[1] = (_Float16)v1;
    *(half2v*)&sm.big.xt[n][c0] = p;
  }
  // zero unused wext rows (4..15)
  for (int z = 4 * 72 + t; z < 16 * 72; z += 256) ((_Float16*)sm.wext)[z] = (_Float16)0.0f;
  // wext rows 0..3: folded score weights  w = a_head^T @ W_head  (fp32 math)
  if (t < 64) {
    int c = t;
    float s0 = 0.f, s1 = 0.f, d0 = 0.f, d1 = 0.f;
    for (int d = 0; d < 32; ++d) {
      s0 += a_src[d]      * Wq[d * 64 + c];
      s1 += a_src[32 + d] * Wq[(32 + d) * 64 + c];
      d0 += a_dst[d]      * Wk[d * 64 + c];
      d1 += a_dst[32 + d] * Wk[(32 + d) * 64 + c];
    }
    sm.wext[0][c] = (_Float16)s0; sm.wext[1][c] = (_Float16)s1;
    sm.wext[2][c] = (_Float16)d0; sm.wext[3][c] = (_Float16)d1;
  }
  __syncthreads();

  const int lane = t & 63, w = t >> 6;
  const int m = lane & 15, quad = lane >> 4;
  const int mbase = w * 64;   // 64 nodes per wave

  float4v acc[4][5];
#pragma unroll
  for (int mt = 0; mt < 4; ++mt)
#pragma unroll
    for (int nt = 0; nt < 5; ++nt)
#pragma unroll
      for (int r = 0; r < 4; ++r) acc[mt][nt][r] = 0.f;

#pragma unroll
  for (int ks = 0; ks < 2; ++ks) {
    half8v af[4], bf[5];
#pragma unroll
    for (int mt = 0; mt < 4; ++mt)
      af[mt] = *(const half8v*)&sm.big.xt[mbase + mt * 16 + m][ks * 32 + quad * 8];
#pragma unroll
    for (int nt = 0; nt < 4; ++nt)
      bf[nt] = *(const half8v*)&sm.wv[nt * 16 + m][ks * 32 + quad * 8];
    bf[4] = *(const half8v*)&sm.wext[m][ks * 32 + quad * 8];
#pragma unroll
    for (int mt = 0; mt < 4; ++mt)
#pragma unroll
      for (int nt = 0; nt < 5; ++nt)
        acc[mt][nt] = __builtin_amdgcn_mfma_f32_16x16x32_f16(af[mt], bf[nt], acc[mt][nt], 0, 0, 0);
  }

  // scatter score columns: n=0 ssrc_h0, 1 ssrc_h1, 2 sdst_h0, 3 sdst_h1
  if (m < 4) {
    float* base = (m < 2 ? s_src_g : s_dst_g) + (size_t)(bt * 2 + (m & 1)) * NDIM;
#pragma unroll
    for (int mt = 0; mt < 4; ++mt)
#pragma unroll
      for (int r = 0; r < 4; ++r)
        base[n0 + mbase + mt * 16 + quad * 4 + r] = acc[mt][4][r];
  }
  __syncthreads();   // all waves done reading xt before overlay

  // V^T bounce into LDS (f16)
#pragma unroll
  for (int mt = 0; mt < 4; ++mt)
#pragma unroll
    for (int nt = 0; nt < 4; ++nt)
#pragma unroll
      for (int r = 0; r < 4; ++r) {
        int node = mbase + mt * 16 + quad * 4 + r;
        int c    = nt * 16 + m;
        sm.big.vt[c][node] = (_Float16)acc[mt][nt][r];
      }
  __syncthreads();

  // coalesced copy V^T -> global  (64 rows x 128 dwords)
  const unsigned* vts = (const unsigned*)sm.big.vt;   // row stride 132 dwords
  unsigned* outdw = (unsigned*)VT_g;
  for (int it = 0; it < 32; ++it) {
    int idx = it * 256 + t;
    int c = idx >> 7, jd = idx & 127;
    outdw[(size_t)(bt * 64 + c) * 256 + half * 128 + jd] = vts[c * 132 + jd];
  }
}

// ============ kernel 2: masked softmax(P) @ V + LayerNorm + transpose ========
// grid (8, NBT): blockIdx.x = i-tile (64 rows), blockIdx.y = bt
struct SmemK2 {
  union {
    _Float16 vt[64][256];   // swizzled V^T half-tile (j half)   32768 B
    float otile[64][65];    // unnormalized O for LN             16640 B
  } big;
  union {
    float sdst[2][512];                                        // 4096 B
    struct { float rsum[4][64]; float rsq[4][64]; float mu[64]; float rs[64]; } ln;
  } u2;
  float ssrc[2][64];        // 512 B
  unsigned maskT[16][64];   // 4096 B
};

__launch_bounds__(256, 3)
__global__ void k2_attn(const _Float16* __restrict__ VT_g,
                        const float* __restrict__ s_src_g, const float* __restrict__ s_dst_g,
                        const unsigned* __restrict__ bits,
                        const float* __restrict__ gamma, const float* __restrict__ beta,
                        float* __restrict__ out) {
  __shared__ SmemK2 sm;
  const int t     = threadIdx.x;
  const int itile = blockIdx.x;
  const int bt    = blockIdx.y;
  const int i0    = itile * 64;
  const int b     = bt / TDIM, tt = bt % TDIM;

  // stage s_dst (all 512 j, both heads)
  for (int it = 0; it < 4; ++it) {
    int idx = it * 256 + t;
    ((float*)sm.u2.sdst)[idx] = s_dst_g[(size_t)bt * 2 * NDIM + idx];
  }
  if (t < 128) {
    int h = t >> 6, i = t & 63;
    sm.ssrc[h][i] = s_src_g[(size_t)(bt * 2 + h) * NDIM + i0 + i];
  }
  for (int it = 0; it < 4; ++it) {
    int idx = it * 256 + t;
    int ks = idx >> 6, i = idx & 63;
    sm.maskT[ks][i] = bits[ks * NDIM + i0 + i];
  }

  const int lane = t & 63, w = t >> 6;
  const int h = w >> 1, ihalf = w & 1;     // wave -> (head, i-half of 32 rows)
  const int m = lane & 15, quad = lane >> 4;

  float4v acc[2][2];
#pragma unroll
  for (int mt = 0; mt < 2; ++mt)
#pragma unroll
    for (int nt = 0; nt < 2; ++nt)
#pragma unroll
      for (int r = 0; r < 4; ++r) acc[mt][nt][r] = 0.f;
  float ssum[2] = {0.f, 0.f};

  __syncthreads();
  float ss[2];
  ss[0] = sm.ssrc[h][ihalf * 32 + m];
  ss[1] = sm.ssrc[h][ihalf * 32 + 16 + m];

  for (int jh = 0; jh < 2; ++jh) {
    if (jh) __syncthreads();   // previous V half fully consumed
    // stage V^T half-tile with XOR swizzle (spreads b128 bank windows)
    const unsigned* src_dw = (const unsigned*)VT_g + (size_t)bt * 64 * 256 + jh * 128;
    unsigned* vdw = (unsigned*)sm.big.vt;   // row stride 128 dwords
    for (int it = 0; it < 32; ++it) {
      int idx = it * 256 + t;
      int c = idx >> 7, jd = idx & 127;
      vdw[c * 128 + (jd ^ ((c & 7) * 4))] = src_dw[(size_t)c * 256 + jd];
    }
    __syncthreads();

#pragma unroll
    for (int ksl = 0; ksl < 8; ++ksl) {
      int ks = jh * 8 + ksl;
      // s_dst chunk for this lane's 8 j's (register copy, shared by both mt)
      const float* dj = &sm.u2.sdst[h][ks * 32 + quad * 8];
      float djv[8];
#pragma unroll
      for (int q = 0; q < 8; ++q) djv[q] = dj[q];

      half8v af[2];
#pragma unroll
      for (int mt = 0; mt < 2; ++mt) {
        unsigned word = sm.maskT[ks][ihalf * 32 + mt * 16 + m];
        unsigned byte = (word >> (quad * 8)) & 0xffu;
        float s = ss[mt];
        half8v a;
        float lsum = 0.f;
#pragma unroll
        for (int jj = 0; jj < 8; ++jj) {
          float xv = s + djv[jj];
          xv = fmaxf(xv, 0.2f * xv);                       // leaky relu
          float e = ((byte >> jj) & 1u) ? __expf(xv - 4.f) : 0.f;  // shift keeps f16 normal
          _Float16 e16 = (_Float16)e;
          a[jj] = e16;
          lsum += (float)e16;                              // sum the f16-rounded weights
        }
        ssum[mt] += lsum;
        af[mt] = a;
      }
      int jo = ksl * 32 + quad * 8;
      int c0 = h * 32 + m, c1 = h * 32 + 16 + m;
      half8v b0 = *(const half8v*)&sm.big.vt[c0][jo ^ ((c0 & 7) * 8)];
      half8v b1 = *(const half8v*)&sm.big.vt[c1][jo ^ ((c1 & 7) * 8)];
      acc[0][0] = __builtin_amdgcn_mfma_f32_16x16x32_f16(af[0], b0, acc[0][0], 0, 0, 0);
      acc[0][1] = __builtin_amdgcn_mfma_f32_16x16x32_f16(af[0], b1, acc[0][1], 0, 0, 0);
      acc[1][0] = __builtin_amdgcn_mfma_f32_16x16x32_f16(af[1], b0, acc[1][0], 0, 0, 0);
      acc[1][1] = __builtin_amdgcn_mfma_f32_16x16x32_f16(af[1], b1, acc[1][1], 0, 0, 0);
    }
  }

  // softmax denominators: reduce partial sums across the 4 quads
#pragma unroll
  for (int mt = 0; mt < 2; ++mt) {
    ssum[mt] += __shfl_xor(ssum[mt], 16);
    ssum[mt] += __shfl_xor(ssum[mt], 32);
  }
  float inv[2] = {1.f / ssum[0], 1.f / ssum[1]};

  __syncthreads();   // all waves done reading vt -> reuse as otile
#pragma unroll
  for (int mt = 0; mt < 2; ++mt)
#pragma unroll
    for (int r = 0; r < 4; ++r) {
      float sv = __shfl(inv[mt], quad * 4 + r);   // denom for row quad*4+r of tile mt
      int i_loc = ihalf * 32 + mt * 16 + quad * 4 + r;
#pragma unroll
      for (int nt = 0; nt < 2; ++nt) {
        int c = h * 32 + nt * 16 + m;
        sm.big.otile[i_loc][c] = acc[mt][nt][r] * sv;
      }
    }
  __syncthreads();

  // LayerNorm over C=64 per row
  {
    int i = t & 63, cg = t >> 6;
    float s1 = 0.f, s2 = 0.f;
#pragma unroll
    for (int cc = 0; cc < 16; ++cc) {
      float v = sm.big.otile[i][cg * 16 + cc];
      s1 += v; s2 += v * v;
    }
    sm.u2.ln.rsum[cg][i] = s1;
    sm.u2.ln.rsq[cg][i]  = s2;
  }
  __syncthreads();
  if (t < 64) {
    int i = t;
    float s1 = 0.f, s2 = 0.f;
#pragma unroll
    for (int cg = 0; cg < 4; ++cg) { s1 += sm.u2.ln.rsum[cg][i]; s2 += sm.u2.ln.rsq[cg][i]; }
    float mu  = s1 * (1.f / 64.f);
    float var = s2 * (1.f / 64.f) - mu * mu;
    sm.u2.ln.mu[i] = mu;
    sm.u2.ln.rs[i] = rsqrtf(var + 1e-5f);
  }
  __syncthreads();
  {
    int i = t & 63, cg = t >> 6;
    float mu = sm.u2.ln.mu[i], rs = sm.u2.ln.rs[i];
    int n = i0 + i;
#pragma unroll
    for (int cc = 0; cc < 16; ++cc) {
      int c = cg * 16 + cc;
      float v = (sm.big.otile[i][c] - mu) * rs * gamma[c] + beta[c];
      out[((size_t)(b * CDIM + c) * TDIM + tt) * NDIM + n] = v;   // (B,C,T,N) coalesced in n
    }
  }
}

// ---------------------------------------------------------------------------
extern "C" void kernel_launch(void* const* d_in, const int* in_sizes, int n_in,
                              void* d_out, int out_size, void* d_ws, size_t ws_size,
                              hipStream_t stream) {
  const float* x     = (const float*)d_in[0];
  const int*   gso   = (const int*)d_in[1];
  const float* Wq    = (const float*)d_in[2];
  const float* Wk    = (const float*)d_in[3];
  const float* Wv    = (const float*)d_in[4];
  const float* a_src = (const float*)d_in[5];
  const float* a_dst = (const float*)d_in[6];
  const float* gamma = (const float*)d_in[7];
  const float* beta  = (const float*)d_in[8];
  float* out = (float*)d_out;

  char* ws = (char*)d_ws;
  _Float16* VT_g   = (_Float16*)ws;
  float*    s_src  = (float*)(ws + 12582912);
  float*    s_dst  = (float*)(ws + 13369344);
  unsigned* bits   = (unsigned*)(ws + 14155776);

  k0_maskbits<<<32, 256, 0, stream>>>(gso, bits);
  k1_qkv<<<dim3(2, NBT), 256, 0, stream>>>(x, Wq, Wk, Wv, a_src, a_dst, VT_g, s_src, s_dst);
  k2_attn<<<dim3(8, NBT), 256, 0, stream>>>(VT_g, s_src, s_dst, bits, gamma, beta, out);
}

// Round 3
// 130.445 us; speedup vs baseline: 1.1183x; 1.1183x over previous
//
#include <hip/hip_runtime.h>

#define CDIM 64
#define TDIM 24
#define NDIM 512
#define NBT  192   // B*T = 8*24

typedef float    float4v __attribute__((ext_vector_type(4)));
typedef _Float16 half8v  __attribute__((ext_vector_type(8)));
typedef _Float16 half2v  __attribute__((ext_vector_type(2)));

// ---------------------------------------------------------------------------
// Workspace layout (bytes):
//   VT_g   : _Float16 [NBT][64][512]   0          (12582912 B)
//   s_src  : float    [NBT][2][512]    12582912   (786432 B)
//   s_dst  : float    [NBT][2][512]    13369344   (786432 B)
//   maskb  : u8       [512][512]       14155776   (262144 B)   {0x00,0xFF}
//   wfold  : float    [4][64]          14417920   (1024 B)
// ---------------------------------------------------------------------------

// ======== kernel 0: byte-mask pack (blocks 0..255) + folded score weights ====
__global__ void k0_prep(const int* __restrict__ gso,
                        const float* __restrict__ Wq, const float* __restrict__ Wk,
                        const float* __restrict__ a_src, const float* __restrict__ a_dst,
                        unsigned* __restrict__ maskb, float* __restrict__ wfold) {
  int t = threadIdx.x;
  if (blockIdx.x < 256) {
    int tg = blockIdx.x * 256 + t;                 // 65536 threads, 4 bytes each
    int4 g = ((const int4*)gso)[tg];
    unsigned w = (g.x ? 0x000000FFu : 0u) | (g.y ? 0x0000FF00u : 0u) |
                 (g.z ? 0x00FF0000u : 0u) | (g.w ? 0xFF000000u : 0u);
    maskb[tg] = w;
  } else {
    // rows: 0=src_h0(Wq) 1=src_h1(Wq) 2=dst_h0(Wk) 3=dst_h1(Wk)
    int r = t >> 6, c = t & 63;
    const float* av = (r & 2) ? a_dst : a_src;
    const float* W  = (r & 2) ? Wk : Wq;
    int off = (r & 1) * 32;
    float s = 0.f;
#pragma unroll
    for (int d = 0; d < 32; ++d)
      s += av[off + d] * W[(off + d) * 64 + c];
    wfold[t] = s;
  }
}

// ======== kernel 1: V = X @ Wv^T (f16 MFMA) + s_src/s_dst extra columns =====
// grid (4, NBT): blockIdx.x = node quarter (128 nodes), blockIdx.y = bt
struct SmemK1 {
  union {
    _Float16 xt[128][72];    // X tile [node][c]  18432 B
    _Float16 vtb[64][136];   // V^T bounce [c][node]  17408 B
  } big;
  _Float16 wv[64][72];       // 9216 B
  _Float16 wext[16][72];     // rows 0..3 = wfold, rest 0  2304 B
};                            // ~29.9 KB

__launch_bounds__(256, 4)
__global__ void k1_v(const float* __restrict__ x, const float* __restrict__ Wv,
                     const float* __restrict__ wfold,
                     _Float16* __restrict__ VT_g,
                     float* __restrict__ s_src_g, float* __restrict__ s_dst_g) {
  __shared__ SmemK1 sm;
  const int t  = threadIdx.x;
  const int qn = blockIdx.x;
  const int bt = blockIdx.y;
  const int b  = bt / TDIM, tt = bt % TDIM;
  const int n0 = qn * 128;

  // stage Wv
  for (int it = 0; it < 16; ++it) {
    int idx = it * 256 + t;
    sm.wv[idx >> 6][idx & 63] = (_Float16)Wv[idx];
  }
  // wext: zero rows 4..15, fill rows 0..3 from wfold
  for (int z = t; z < 12 * 72; z += 256) ((_Float16*)sm.wext[4])[z] = (_Float16)0.f;
  {
    int r = t >> 6, c = t & 63;
    sm.wext[r][c] = (_Float16)wfold[t];
  }
  // stage X tile (channel pairs -> half2)
  for (int it = 0; it < 16; ++it) {
    int idx = it * 256 + t;
    int cp = idx >> 7, n = idx & 127;
    int c0 = cp * 2;
    const float* base = x + ((size_t)(b * CDIM + c0) * TDIM + tt) * NDIM + n0 + n;
    half2v p; p[0] = (_Float16)base[0]; p[1] = (_Float16)base[(size_t)TDIM * NDIM];
    *(half2v*)&sm.big.xt[n][c0] = p;
  }
  __syncthreads();

  const int lane = t & 63, w = t >> 6;
  const int m = lane & 15, quad = lane >> 4;
  const int mbase = w * 32;   // 32 nodes per wave

  float4v acc[2][5];
#pragma unroll
  for (int mt = 0; mt < 2; ++mt)
#pragma unroll
    for (int nt = 0; nt < 5; ++nt)
#pragma unroll
      for (int r = 0; r < 4; ++r) acc[mt][nt][r] = 0.f;

#pragma unroll
  for (int ks = 0; ks < 2; ++ks) {
    half8v af[2], bf[5];
#pragma unroll
    for (int mt = 0; mt < 2; ++mt)
      af[mt] = *(const half8v*)&sm.big.xt[mbase + mt * 16 + m][ks * 32 + quad * 8];
#pragma unroll
    for (int nt = 0; nt < 4; ++nt)
      bf[nt] = *(const half8v*)&sm.wv[nt * 16 + m][ks * 32 + quad * 8];
    bf[4] = *(const half8v*)&sm.wext[m][ks * 32 + quad * 8];
#pragma unroll
    for (int mt = 0; mt < 2; ++mt)
#pragma unroll
      for (int nt = 0; nt < 5; ++nt)
        acc[mt][nt] = __builtin_amdgcn_mfma_f32_16x16x32_f16(af[mt], bf[nt], acc[mt][nt], 0, 0, 0);
  }

  // scatter score columns (col 0/1 = ssrc h0/h1, col 2/3 = sdst h0/h1)
  if (m < 4) {
    float* basep = (m < 2 ? s_src_g : s_dst_g) + (size_t)(bt * 2 + (m & 1)) * NDIM;
#pragma unroll
    for (int mt = 0; mt < 2; ++mt)
#pragma unroll
      for (int r = 0; r < 4; ++r)
        basep[n0 + mbase + mt * 16 + quad * 4 + r] = acc[mt][4][r];
  }
  __syncthreads();   // xt fully consumed before overlay

  // V^T bounce into LDS (pack node pairs)
#pragma unroll
  for (int mt = 0; mt < 2; ++mt)
#pragma unroll
    for (int nt = 0; nt < 4; ++nt)
#pragma unroll
      for (int r = 0; r < 4; r += 2) {
        int nl = mbase + mt * 16 + quad * 4 + r;
        int c  = nt * 16 + m;
        half2v p = __builtin_bit_cast(half2v,
            __builtin_amdgcn_cvt_pkrtz(acc[mt][nt][r], acc[mt][nt][r + 1]));
        *(half2v*)&sm.big.vtb[c][nl] = p;
      }
  __syncthreads();

  // coalesced V^T -> global (64 rows x 64 dwords)
  const unsigned* vdw = (const unsigned*)sm.big.vtb;   // row stride 68 dwords
  unsigned* outdw = (unsigned*)VT_g;
  for (int it = 0; it < 16; ++it) {
    int idx = it * 256 + t;
    int c = idx >> 6, jd = idx & 63;
    outdw[(size_t)(bt * 64 + c) * 256 + qn * 64 + jd] = vdw[c * 68 + jd];
  }
}

// ======== kernel 2: masked softmax(P) @ V + LayerNorm + transpose ===========
// grid (8, NBT): blockIdx.x = i-tile (64 rows), blockIdx.y = bt
struct SmemK2 {
  union {
    struct { _Float16 vt[64][128]; unsigned char mb[64][144]; } s;  // 16384+9216=25600
    struct { float otile[64][66]; float rsum[4][64]; float rsq[4][64];
             float mu[64]; float rs[64]; } e;                        // 21504
  } u;
  float sdst[2][512];   // 4096
};                       // 29696 B

__launch_bounds__(256, 4)
__global__ void k2_attn(const _Float16* __restrict__ VT_g,
                        const float* __restrict__ s_src_g, const float* __restrict__ s_dst_g,
                        const unsigned char* __restrict__ maskb,
                        const float* __restrict__ gamma, const float* __restrict__ beta,
                        float* __restrict__ out) {
  __shared__ SmemK2 sm;
  const int t     = threadIdx.x;
  const int itile = blockIdx.x;
  const int bt    = blockIdx.y;
  const int i0    = itile * 64;
  const int b     = bt / TDIM, tt = bt % TDIM;
  const int lane  = t & 63, w = t >> 6;
  const int h = w >> 1, ihalf = w & 1;
  const int m = lane & 15, quad = lane >> 4;

  // stage s_dst (raw)
  for (int it = 0; it < 4; ++it) {
    int idx = it * 256 + t;
    ((float*)sm.sdst)[idx] = s_dst_g[(size_t)bt * 2 * NDIM + idx];
  }
  // per-row source terms with folded bias: exp(lrelu(s+d) - 4)
  float s1r[2], s2r[2];
#pragma unroll
  for (int mt = 0; mt < 2; ++mt) {
    float sv = s_src_g[(size_t)(bt * 2 + h) * NDIM + i0 + ihalf * 32 + mt * 16 + m];
    s1r[mt] = sv - 4.f;
    s2r[mt] = 0.2f * sv - 4.f;
  }

  float4v acc[2][2], accs[2];
#pragma unroll
  for (int mt = 0; mt < 2; ++mt) {
#pragma unroll
    for (int r = 0; r < 4; ++r) { acc[mt][0][r] = 0.f; acc[mt][1][r] = 0.f; accs[mt][r] = 0.f; }
  }
  const half8v bones = {(_Float16)1.f, (_Float16)1.f, (_Float16)1.f, (_Float16)1.f,
                        (_Float16)1.f, (_Float16)1.f, (_Float16)1.f, (_Float16)1.f};

  for (int js = 0; js < 4; ++js) {
    __syncthreads();
    // stage V^T quarter (swizzled 16B chunks)
    {
      const uint4* vsrc = (const uint4*)VT_g;
#pragma unroll
      for (int it = 0; it < 4; ++it) {
        int idx = it * 256 + t;
        int c = idx >> 4, ch = idx & 15;
        uint4 val = vsrc[(size_t)(bt * 64 + c) * 64 + js * 16 + ch];
        *(uint4*)&sm.u.s.vt[c][(ch * 8) ^ ((c & 7) * 8)] = val;
      }
#pragma unroll
      for (int it = 0; it < 2; ++it) {
        int idx = it * 256 + t;
        int c = idx >> 3, ch = idx & 7;
        uint4 mv = *(const uint4*)(maskb + (size_t)(i0 + c) * NDIM + js * 128 + ch * 16);
        *(uint4*)&sm.u.s.mb[c][ch * 16] = mv;
      }
    }
    __syncthreads();

#pragma unroll
    for (int ksl = 0; ksl < 4; ++ksl) {
      int jq = ksl * 32 + quad * 8;   // j within quarter
      float4v dj0 = *(const float4v*)&sm.sdst[h][js * 128 + jq];
      float4v dj1 = *(const float4v*)&sm.sdst[h][js * 128 + jq + 4];
      int vbase = (h * 32 + m) * 128 + (jq ^ ((m & 7) * 8));
      half8v b0 = *(const half8v*)&sm.u.s.vt[0][vbase];
      half8v b1 = *(const half8v*)&sm.u.s.vt[0][vbase + 16 * 128];
#pragma unroll
      for (int mt = 0; mt < 2; ++mt) {
        const unsigned* mwp = (const unsigned*)&sm.u.s.mb[ihalf * 32 + mt * 16 + m][jq];
        unsigned mw0 = mwp[0], mw1 = mwp[1];
        float e[8];
#pragma unroll
        for (int jj = 0; jj < 8; ++jj) {
          float d = (jj < 4) ? dj0[jj] : dj1[jj - 4];
          float f1 = s1r[mt] + d;
          float f2 = __builtin_fmaf(d, 0.2f, s2r[mt]);
          e[jj] = __expf(fmaxf(f1, f2));
        }
        unsigned p0 = __builtin_bit_cast(unsigned, __builtin_amdgcn_cvt_pkrtz(e[0], e[1]))
                      & __builtin_amdgcn_perm(0u, mw0, 0x01010000u);
        unsigned p1 = __builtin_bit_cast(unsigned, __builtin_amdgcn_cvt_pkrtz(e[2], e[3]))
                      & __builtin_amdgcn_perm(0u, mw0, 0x03030202u);
        unsigned p2 = __builtin_bit_cast(unsigned, __builtin_amdgcn_cvt_pkrtz(e[4], e[5]))
                      & __builtin_amdgcn_perm(0u, mw1, 0x01010000u);
        unsigned p3 = __builtin_bit_cast(unsigned, __builtin_amdgcn_cvt_pkrtz(e[6], e[7]))
                      & __builtin_amdgcn_perm(0u, mw1, 0x03030202u);
        uint4 au; au.x = p0; au.y = p1; au.z = p2; au.w = p3;
        half8v af = __builtin_bit_cast(half8v, au);
        acc[mt][0] = __builtin_amdgcn_mfma_f32_16x16x32_f16(af, b0,    acc[mt][0], 0, 0, 0);
        acc[mt][1] = __builtin_amdgcn_mfma_f32_16x16x32_f16(af, b1,    acc[mt][1], 0, 0, 0);
        accs[mt]   = __builtin_amdgcn_mfma_f32_16x16x32_f16(af, bones, accs[mt],   0, 0, 0);
      }
    }
  }

  __syncthreads();   // vt/mb dead -> otile overlay
  // normalize by row sums (same C-layout row as acc -> no shuffle needed)
#pragma unroll
  for (int mt = 0; mt < 2; ++mt)
#pragma unroll
    for (int r = 0; r < 4; ++r) {
      float sc = __builtin_amdgcn_rcpf(accs[mt][r]);
      int i_loc = ihalf * 32 + mt * 16 + quad * 4 + r;
#pragma unroll
      for (int nt = 0; nt < 2; ++nt)
        sm.u.e.otile[i_loc][h * 32 + nt * 16 + m] = acc[mt][nt][r] * sc;
    }
  __syncthreads();

  // LayerNorm over C=64 per row
  {
    int i = t & 63, cg = t >> 6;
    float s1 = 0.f, s2 = 0.f;
#pragma unroll
    for (int cc = 0; cc < 16; ++cc) {
      float v = sm.u.e.otile[i][cg * 16 + cc];
      s1 += v; s2 += v * v;
    }
    sm.u.e.rsum[cg][i] = s1;
    sm.u.e.rsq[cg][i]  = s2;
  }
  __syncthreads();
  if (t < 64) {
    int i = t;
    float s1 = 0.f, s2 = 0.f;
#pragma unroll
    for (int cg = 0; cg < 4; ++cg) { s1 += sm.u.e.rsum[cg][i]; s2 += sm.u.e.rsq[cg][i]; }
    float mu  = s1 * (1.f / 64.f);
    float var = s2 * (1.f / 64.f) - mu * mu;
    sm.u.e.mu[i] = mu;
    sm.u.e.rs[i] = rsqrtf(var + 1e-5f);
  }
  __syncthreads();
  {
    int i = t & 63, cg = t >> 6;
    float mu = sm.u.e.mu[i], rs = sm.u.e.rs[i];
    int n = i0 + i;
#pragma unroll
    for (int cc = 0; cc < 16; ++cc) {
      int c = cg * 16 + cc;
      float v = (sm.u.e.otile[i][c] - mu) * rs * gamma[c] + beta[c];
      out[((size_t)(b * CDIM + c) * TDIM + tt) * NDIM + n] = v;
    }
  }
}

// ---------------------------------------------------------------------------
extern "C" void kernel_launch(void* const* d_in, const int* in_sizes, int n_in,
                              void* d_out, int out_size, void* d_ws, size_t ws_size,
                              hipStream_t stream) {
  const float* x     = (const float*)d_in[0];
  const int*   gso   = (const int*)d_in[1];
  const float* Wq    = (const float*)d_in[2];
  const float* Wk    = (const float*)d_in[3];
  const float* Wv    = (const float*)d_in[4];
  const float* a_src = (const float*)d_in[5];
  const float* a_dst = (const float*)d_in[6];
  const float* gamma = (const float*)d_in[7];
  const float* beta  = (const float*)d_in[8];
  float* out = (float*)d_out;

  char* ws = (char*)d_ws;
  _Float16* VT_g  = (_Float16*)ws;
  float*    s_src = (float*)(ws + 12582912);
  float*    s_dst = (float*)(ws + 13369344);
  unsigned char* maskb = (unsigned char*)(ws + 14155776);
  float*    wfold = (float*)(ws + 14417920);

  k0_prep<<<257, 256, 0, stream>>>(gso, Wq, Wk, a_src, a_dst, (unsigned*)maskb, wfold);
  k1_v<<<dim3(4, NBT), 256, 0, stream>>>(x, Wv, wfold, VT_g, s_src, s_dst);
  k2_attn<<<dim3(8, NBT), 256, 0, stream>>>(VT_g, s_src, s_dst, maskb, gamma, beta, out);
}